// Round 7
// baseline (242.346 us; speedup 1.0000x reference)
//
#include <hip/hip_runtime.h>
#include <math.h>

#define L_IN     262144
#define N_FRAME  1024
#define AMIN     1e-10f
#define DRANGE   80.0f
#define UNITS_CH 1056            // (32 frames * 256 hop + 256)/8 16B-units per channel
#define WS_HI_OFF   4096
#define WS_HALF     524288       // 16 frags * 32 kk * 64 lanes * 16B
#define N4_OUT   ((32 * 257 * 1024 * 2) / 4)

// LDS map (bytes): A 0..67583 (S epilogue buffer overlaps A);
// W hi ring 3-deep @67584 (8g x 3d x 2nf x 1KB = 48K); W lo ring 2-deep @116736 (32K).
#define A_BYTES   67584
#define WH_OFF    67584
#define WL_OFF    116736
#define SMEM_BYTES 149504

typedef short bf16x8 __attribute__((ext_vector_type(8)));
typedef short bf16x4 __attribute__((ext_vector_type(4)));
typedef float f32x16 __attribute__((ext_vector_type(16)));

typedef __attribute__((address_space(1))) const void av1_t;
typedef __attribute__((address_space(3))) void av3_t;
__device__ __forceinline__ void gload_lds16(const void* g, void* l) {
    // async global->LDS DMA, 16B/lane; LDS dest = wave-uniform base + lane*16 (m104)
    __builtin_amdgcn_global_load_lds((av1_t*)g, (av3_t*)l, 16, 0, 0);
}

__device__ __forceinline__ short f2bf(float f) {           // fp32 -> bf16 RNE
    unsigned u = __float_as_uint(f);
    u = (u + 0x7FFFu + ((u >> 16) & 1u)) >> 16;
    return (short)u;
}
__device__ __forceinline__ float bf2f(short h) {
    return __uint_as_float(((unsigned)(unsigned short)h) << 16);
}
__device__ __forceinline__ int swz(int u) { return u ^ ((u >> 5) & 7); }

// W -> bf16 hi/lo in 32x32x16 MFMA B-frag order.  (unchanged)
__global__ __launch_bounds__(256) void wconv_kernel(
    const float* __restrict__ kr, const float* __restrict__ ki,
    short* __restrict__ whi, short* __restrict__ wlo, unsigned* __restrict__ wsmax)
{
    if (blockIdx.x == 0 && threadIdx.x == 0) wsmax[0] = 0u;
    const int tid  = threadIdx.x;
    const int pair = blockIdx.x * 4 + (tid >> 6);   // (fi,kk) in [0,512)
    const int lane = tid & 63;
    const int fi = pair >> 5, kk = pair & 31;
    const int g = fi >> 1, nf = fi & 1;
    const int n  = lane & 31;
    const int k0 = kk * 16 + (lane >> 5) * 8;
    const int f  = g * 32 + n;
    bf16x8 h8, l8;
    #pragma unroll
    for (int j = 0; j < 8; ++j) {
        const int k = k0 + j;
        float w;
        if (nf == 1 && g == 0 && n == 0) w = kr[k * 257 + 256];   // Nyquist column
        else                             w = (nf ? ki : kr)[k * 257 + f];
        short hh = f2bf(w);
        h8[j] = hh;
        l8[j] = f2bf(w - bf2f(hh));
    }
    const int off = ((fi * 32 + kk) * 64 + lane) * 8;
    *(bf16x8*)(whi + off) = h8;
    *(bf16x8*)(wlo + off) = l8;
}

// One block: 32 frames x 2 channels (M=64) x all 257 filters; 8 waves, wave = filter group.
// ASYNC-PIPELINED K-loop: W streamed HBM/L2 -> LDS ring via global_load_lds (per-wave
// private slices, NO barriers), counted s_waitcnt vmcnt(6) so 6 DMA ops stay in flight
// across each phase's MFMAs (T3/T4).  hi ring 3-deep (2-phase lookahead), lo 2-deep.
// 1 block/CU (149.5 KB LDS) — trades occupancy for pipeline depth, per the 8-phase
// template evidence (62% MfmaUtil at 8 waves/CU).  Plain launch_bounds: no reg cap
// (round-1 lesson).
__global__ __launch_bounds__(512) void spec_kernel(
    const float* __restrict__ x,
    const short* __restrict__ whi, const short* __restrict__ wlo,
    float* __restrict__ out, unsigned* __restrict__ wsmax)
{
    __shared__ __align__(16) char smem[SMEM_BYTES];
    __shared__ float wmax[8];
    short* Ah = (short*)smem;                                   // 33792 B
    short* Al = (short*)(smem + A_BYTES / 2);
    float* S  = (float*)smem;                                   // [64][257] = 65792 B

    const int blk = blockIdx.x;
    const int tt  = blk & 31;
    const int b   = blk >> 5;
    const int tid = threadIdx.x;
    const int lane = tid & 63;
    const int g    = tid >> 6;          // wave = filter group
    const int col  = lane & 31;
    const int half = lane >> 5;

    // per-lane global W bases (shorts); kk stride 512 shorts (1KB), nf stride 16384
    const short* wgH = whi + (g * 2) * 32 * 64 * 8 + lane * 8;
    const short* wgL = wlo + (g * 2) * 32 * 64 * 8 + lane * 8;

    // ---- prologue DMAs (land during stage-A; barrier's vmcnt(0) drain is fine) ----
    gload_lds16(wgL,                 smem + WL_OFF + ((g * 2 + 0) * 2 + 0) * 1024); // lo[0]
    gload_lds16(wgL + 16384,         smem + WL_OFF + ((g * 2 + 0) * 2 + 1) * 1024);
    gload_lds16(wgH,                 smem + WH_OFF + ((g * 3 + 0) * 2 + 0) * 1024); // hi[0]
    gload_lds16(wgH + 16384,         smem + WH_OFF + ((g * 3 + 0) * 2 + 1) * 1024);
    gload_lds16(wgH + 512,           smem + WH_OFF + ((g * 3 + 1) * 2 + 0) * 1024); // hi[1]
    gload_lds16(wgH + 16384 + 512,   smem + WH_OFF + ((g * 3 + 1) * 2 + 1) * 1024);

    // ---- stage A: rolled; wave-contiguous 256-sample chunks (round-6, verified) ----
    const int s_origin = tt * 8192 - 128;
    for (int cc = g; cc < 66; cc += 8) {
        const int ch   = (cc >= 33) ? 1 : 0;
        const int c    = cc - ch * 33;
        const int base = s_origin + c * 256;
        const float* xp = x + ((size_t)b * 2 + ch) * L_IN;
        const int i4 = base + lane * 4;
        float v[4];
        if (base >= 0 && base + 256 <= L_IN) {
            float4 p = *(const float4*)(xp + i4);
            v[0] = p.x; v[1] = p.y; v[2] = p.z; v[3] = p.w;
        } else {
            #pragma unroll
            for (int j = 0; j < 4; ++j) {
                const int idx = i4 + j;
                v[j] = (idx >= 0 && idx < L_IN) ? xp[idx] : 0.0f;
            }
        }
        bf16x4 h4, l4;
        #pragma unroll
        for (int j = 0; j < 4; ++j) {
            short hh = f2bf(v[j]);
            h4[j] = hh;
            l4[j] = f2bf(v[j] - bf2f(hh));
        }
        const int u = c * 32 + (lane >> 1);
        const int e = (ch * UNITS_CH + swz(u)) * 8 + (lane & 1) * 4;
        *(bf16x4*)&Ah[e] = h4;
        *(bf16x4*)&Al[e] = l4;
    }
    __syncthreads();

    // ---- K loop: 32 phases, per-wave async W pipeline ----
    f32x16 acc[2][2];                  // [mf(channel)][nf(cos/sin)]
    #pragma unroll
    for (int mf = 0; mf < 2; ++mf)
        #pragma unroll
        for (int nf = 0; nf < 2; ++nf)
            #pragma unroll
            for (int r = 0; r < 16; ++r) acc[mf][nf][r] = 0.0f;

    int d3 = 0;                        // = s % 3 (hi ring read slot)
    for (int s = 0; s < 32; ++s) {
        // batch s: issue lo[s+1] (slot (s+1)&1), hi[s+2] (slot (s+2)%3); wrap at tail
        const int kkL = (s + 1) & 31;
        const int kkH = (s + 2) & 31;
        const int dL = (s + 1) & 1;
        const int dH = (d3 == 0) ? 2 : d3 - 1;      // (s+2)%3
        gload_lds16(wgL + kkL * 512,         smem + WL_OFF + ((g * 2 + dL) * 2 + 0) * 1024);
        gload_lds16(wgL + 16384 + kkL * 512, smem + WL_OFF + ((g * 2 + dL) * 2 + 1) * 1024);
        gload_lds16(wgH + kkH * 512,         smem + WH_OFF + ((g * 3 + dH) * 2 + 0) * 1024);
        gload_lds16(wgH + 16384 + kkH * 512, smem + WH_OFF + ((g * 3 + dH) * 2 + 1) * 1024);
        // counted wait: drains exactly hi[s], lo[s]; leaves 6 in flight (never 0)
        asm volatile("s_waitcnt vmcnt(6)" ::: "memory");

        const int hbase = WH_OFF + (g * 3 + d3) * 2048 + lane * 16;
        const int lbase = WL_OFF + (g * 2 + (s & 1)) * 2048 + lane * 16;
        bf16x8 bh0 = *(const bf16x8*)(smem + hbase);
        bf16x8 bh1 = *(const bf16x8*)(smem + hbase + 1024);
        bf16x8 bl0 = *(const bf16x8*)(smem + lbase);
        bf16x8 bl1 = *(const bf16x8*)(smem + lbase + 1024);

        const int u0 = col * 32 + s * 2 + half;
        const int e0 = swz(u0) * 8;
        const int e1 = (UNITS_CH + swz(u0)) * 8;
        bf16x8 ah0 = *(const bf16x8*)&Ah[e0];
        bf16x8 ah1 = *(const bf16x8*)&Ah[e1];
        bf16x8 al0 = *(const bf16x8*)&Al[e0];
        bf16x8 al1 = *(const bf16x8*)&Al[e1];

        // hh
        acc[0][0] = __builtin_amdgcn_mfma_f32_32x32x16_bf16(ah0, bh0, acc[0][0], 0, 0, 0);
        acc[0][1] = __builtin_amdgcn_mfma_f32_32x32x16_bf16(ah0, bh1, acc[0][1], 0, 0, 0);
        acc[1][0] = __builtin_amdgcn_mfma_f32_32x32x16_bf16(ah1, bh0, acc[1][0], 0, 0, 0);
        acc[1][1] = __builtin_amdgcn_mfma_f32_32x32x16_bf16(ah1, bh1, acc[1][1], 0, 0, 0);
        // hl
        acc[0][0] = __builtin_amdgcn_mfma_f32_32x32x16_bf16(ah0, bl0, acc[0][0], 0, 0, 0);
        acc[0][1] = __builtin_amdgcn_mfma_f32_32x32x16_bf16(ah0, bl1, acc[0][1], 0, 0, 0);
        acc[1][0] = __builtin_amdgcn_mfma_f32_32x32x16_bf16(ah1, bl0, acc[1][0], 0, 0, 0);
        acc[1][1] = __builtin_amdgcn_mfma_f32_32x32x16_bf16(ah1, bl1, acc[1][1], 0, 0, 0);
        // lh
        acc[0][0] = __builtin_amdgcn_mfma_f32_32x32x16_bf16(al0, bh0, acc[0][0], 0, 0, 0);
        acc[0][1] = __builtin_amdgcn_mfma_f32_32x32x16_bf16(al0, bh1, acc[0][1], 0, 0, 0);
        acc[1][0] = __builtin_amdgcn_mfma_f32_32x32x16_bf16(al1, bh0, acc[1][0], 0, 0, 0);
        acc[1][1] = __builtin_amdgcn_mfma_f32_32x32x16_bf16(al1, bh1, acc[1][1], 0, 0, 0);

        d3 = (d3 == 2) ? 0 : d3 + 1;
    }

    // ---- epilogue: p = re^2+im^2 -> LDS transpose S[64][257] -> coalesced stores ----
    // C/D layout (32x32): n = lane&31, m = (r&3) + 8*(r>>2) + 4*(lane>>5)
    __syncthreads();                       // all A-reads done; reuse LDS as S
    const bool nyq = (g == 0) && (col == 0);
    float pmax = 0.0f;
    #pragma unroll
    for (int mf = 0; mf < 2; ++mf) {       // mf = channel
        #pragma unroll
        for (int r = 0; r < 16; ++r) {
            const int m   = (r & 3) + 8 * (r >> 2) + 4 * half;
            const int row = m * 2 + mf;
            const float re = acc[mf][0][r];
            const float im = acc[mf][1][r];
            const float imq = nyq ? 0.0f : im;
            float p = fmaxf(re * re + imq * imq, AMIN);
            pmax = fmaxf(pmax, p);
            S[row * 257 + g * 32 + col] = p;   // bank (row+col)%32: conflict-free
            if (nyq) {                     // sin-frag col0 carries f=256 re
                float pn = fmaxf(im * im, AMIN);
                pmax = fmaxf(pmax, pn);
                S[row * 257 + 256] = pn;
            }
        }
    }
    #pragma unroll
    for (int off = 32; off > 0; off >>= 1)
        pmax = fmaxf(pmax, __shfl_down(pmax, off, 64));
    if (lane == 0) wmax[g] = pmax;
    __syncthreads();                       // guards both wmax and S
    if (tid == 0) {
        float m2 = wmax[0];
        #pragma unroll
        for (int w = 1; w < 8; ++w) m2 = fmaxf(m2, wmax[w]);
        atomicMax(wsmax, __float_as_uint(m2));
    }
    // per f: 64 consecutive floats (t local 0..31 x mf) = 16 float4; 4112 float4 total
    float* obase = out + (size_t)b * 526336 + (size_t)tt * 64;
    for (int q = tid; q < 257 * 16; q += 512) {
        const int f = q >> 4, part = q & 15;
        float4 vv;
        vv.x = S[(part * 4 + 0) * 257 + f];
        vv.y = S[(part * 4 + 1) * 257 + f];
        vv.z = S[(part * 4 + 2) * 257 + f];
        vv.w = S[(part * 4 + 3) * 257 + f];
        *(float4*)(obase + (size_t)f * 2048 + part * 4) = vv;
    }
}

__global__ __launch_bounds__(256) void finalize_kernel(
    float* __restrict__ out, const unsigned* __restrict__ ws_max, int n4)
{
    const int i = blockIdx.x * 256 + threadIdx.x;
    if (i >= n4) return;
    const float mlog = 10.0f * log10f(__uint_as_float(*ws_max));
    float4 p = ((const float4*)out)[i];
    float4 v;
    v.x = fmaxf(10.0f * log10f(p.x) - mlog, -DRANGE);
    v.y = fmaxf(10.0f * log10f(p.y) - mlog, -DRANGE);
    v.z = fmaxf(10.0f * log10f(p.z) - mlog, -DRANGE);
    v.w = fmaxf(10.0f * log10f(p.w) - mlog, -DRANGE);
    ((float4*)out)[i] = v;
}

extern "C" void kernel_launch(void* const* d_in, const int* in_sizes, int n_in,
                              void* d_out, int out_size, void* d_ws, size_t ws_size,
                              hipStream_t stream) {
    const float* x  = (const float*)d_in[0];
    const float* kr = (const float*)d_in[1];
    const float* ki = (const float*)d_in[2];
    float* out      = (float*)d_out;

    unsigned* wsmax = (unsigned*)d_ws;
    short* whi      = (short*)((char*)d_ws + WS_HI_OFF);
    short* wlo      = (short*)((char*)d_ws + WS_HI_OFF + WS_HALF);

    wconv_kernel<<<128, 256, 0, stream>>>(kr, ki, whi, wlo, wsmax);

    const int nblocks = 32 * 32;       // b * t-tiles (32 frames per tile)
    spec_kernel<<<nblocks, 512, 0, stream>>>(x, whi, wlo, out, wsmax);

    const int n4 = N4_OUT;
    finalize_kernel<<<(n4 + 255) / 256, 256, 0, stream>>>(out, wsmax, n4);
}

// Round 8
// 229.879 us; speedup vs baseline: 1.0542x; 1.0542x over previous
//
#include <hip/hip_runtime.h>
#include <math.h>

#define L_IN     262144
#define N_FRAME  1024
#define AMIN     1e-10f
#define DRANGE   80.0f
#define WS_HI_OFF   4096
#define WS_HALF     524288       // 16 frags * 32 kk * 64 lanes * 16B
#define N4_OUT   ((32 * 257 * 1024 * 2) / 4)

// LDS map: A ring 2 x {hi 2KB, lo 2KB} @0..8191; W ring 2 x 8waves x 4KB @8192..73727.
// Epilogue S[64][257] (65792B) overlays the rings after the final barrier.
#define ARING_OFF 0
#define WRING_OFF 8192
#define SMEM_BYTES 73728

typedef short bf16x8 __attribute__((ext_vector_type(8)));
typedef float f32x16 __attribute__((ext_vector_type(16)));

typedef __attribute__((address_space(1))) const void av1_t;
typedef __attribute__((address_space(3))) void av3_t;
__device__ __forceinline__ void gload_lds16(const void* g, void* l) {
    __builtin_amdgcn_global_load_lds((av1_t*)g, (av3_t*)l, 16, 0, 0);
}

__device__ __forceinline__ short f2bf(float f) {           // fp32 -> bf16 RNE
    unsigned u = __float_as_uint(f);
    u = (u + 0x7FFFu + ((u >> 16) & 1u)) >> 16;
    return (short)u;
}
__device__ __forceinline__ float bf2f(short h) {
    return __uint_as_float(((unsigned)(unsigned short)h) << 16);
}

// W -> bf16 hi/lo in 32x32x16 MFMA B-frag order.  (unchanged, verified)
__global__ __launch_bounds__(256) void wconv_kernel(
    const float* __restrict__ kr, const float* __restrict__ ki,
    short* __restrict__ whi, short* __restrict__ wlo, unsigned* __restrict__ wsmax)
{
    if (blockIdx.x == 0 && threadIdx.x == 0) wsmax[0] = 0u;
    const int tid  = threadIdx.x;
    const int pair = blockIdx.x * 4 + (tid >> 6);   // (fi,kk) in [0,512)
    const int lane = tid & 63;
    const int fi = pair >> 5, kk = pair & 31;
    const int g = fi >> 1, nf = fi & 1;
    const int n  = lane & 31;
    const int k0 = kk * 16 + (lane >> 5) * 8;
    const int f  = g * 32 + n;
    bf16x8 h8, l8;
    #pragma unroll
    for (int j = 0; j < 8; ++j) {
        const int k = k0 + j;
        float w;
        if (nf == 1 && g == 0 && n == 0) w = kr[k * 257 + 256];   // Nyquist column
        else                             w = (nf ? ki : kr)[k * 257 + f];
        short hh = f2bf(w);
        h8[j] = hh;
        l8[j] = f2bf(w - bf2f(hh));
    }
    const int off = ((fi * 32 + kk) * 64 + lane) * 8;
    *(bf16x8*)(whi + off) = h8;
    *(bf16x8*)(wlo + off) = l8;
}

// One block: 32 frames x 2 ch (M=64) x 257 filters; 8 waves, wave = filter group.
// PHASE-LOCKED double-buffered pipeline (T3+T4 with prerequisites met):
//   per phase kk: {2 A-loads + 4 W-DMAs for kk+1} -> vmcnt(6) (counted, never 0)
//   -> 8 ds_read frags -> 12 MFMA -> convert+ds_write A[kk+1] -> lgkmcnt(0)
//   -> raw s_barrier (no vmcnt(0) drain).
// LDS 72KB -> 2 blocks/CU (16 waves): r7's occupancy loss fixed.  All LDS access
// linear/uniform (no swizzle needed) -> bank conflicts should collapse.
__global__ __launch_bounds__(512) void spec_kernel(
    const float* __restrict__ x,
    const short* __restrict__ whi, const short* __restrict__ wlo,
    float* __restrict__ out, unsigned* __restrict__ wsmax)
{
    __shared__ __align__(16) char smem[SMEM_BYTES];
    __shared__ float wmax[8];
    float* S = (float*)smem;            // [64][257] epilogue overlay

    const int blk = blockIdx.x;
    const int tt  = blk & 31;
    const int b   = blk >> 5;
    const int tid = threadIdx.x;
    const int lane = tid & 63;
    const int g    = tid >> 6;          // wave = filter group
    const int col  = lane & 31;
    const int half = lane >> 5;

    // per-lane global W bases (shorts); kk stride 512 shorts (1KB), nf stride 16384
    const short* wgH = whi + (g * 2) * 32 * 64 * 8 + lane * 8;
    const short* wgL = wlo + (g * 2) * 32 * 64 * 8 + lane * 8;

    // A staging decomposition: thread t covers samples [j2, j2+2) of ring unit q.
    // unit q = mf*64 + col*2 + half  <->  signal unit u = col*32 + kk*2 + half.
    const int s_origin = tt * 8192 - 128;
    const int q    = tid >> 2;
    const int j2   = (tid & 3) * 2;
    const int mfst = q >> 6;
    const int cc   = q & 63;
    const int ubase = (cc >> 1) * 32 + (cc & 1);
    const float* xst = x + ((size_t)b * 2 + mfst) * L_IN;
    const int ibase = s_origin + ubase * 8 + j2;
    const int a_waddr = q * 16 + (tid & 3) * 4;          // byte offset in A buf
    // A-read frag offsets (per lane)
    const int ard0 = (col * 2 + half) * 16;              // mf=0
    const int ard1 = (64 + col * 2 + half) * 16;         // mf=1

    // ---- prologue: issue W[0] DMAs; stage A[0]; publish ----
    {
        char* wb = smem + WRING_OFF + g * 4096;          // buf 0
        gload_lds16(wgH,         wb);
        gload_lds16(wgH + 16384, wb + 1024);
        gload_lds16(wgL,         wb + 2048);
        gload_lds16(wgL + 16384, wb + 3072);
        const int i0 = ibase;                            // kk = 0
        const bool o0 = (i0 >= 0) && (i0 < L_IN);
        const bool o1 = (i0 + 1 >= 0) && (i0 + 1 < L_IN);
        const int c0 = i0 < 0 ? 0 : (i0 >= L_IN ? L_IN - 1 : i0);
        const int c1 = (i0 + 1) < 0 ? 0 : ((i0 + 1) >= L_IN ? L_IN - 1 : (i0 + 1));
        float v0 = xst[c0]; if (!o0) v0 = 0.0f;
        float v1 = xst[c1]; if (!o1) v1 = 0.0f;
        short h0 = f2bf(v0), h1 = f2bf(v1);
        short l0 = f2bf(v0 - bf2f(h0)), l1 = f2bf(v1 - bf2f(h1));
        *(unsigned*)(smem + ARING_OFF + a_waddr) =
            (unsigned)(unsigned short)h0 | ((unsigned)(unsigned short)h1 << 16);
        *(unsigned*)(smem + ARING_OFF + 2048 + a_waddr) =
            (unsigned)(unsigned short)l0 | ((unsigned)(unsigned short)l1 << 16);
        asm volatile("s_waitcnt lgkmcnt(0)" ::: "memory");
        __builtin_amdgcn_s_barrier();
    }
    // steady state entering each phase: 4 W-DMAs outstanding (for cur)

    f32x16 acc[2][2];                  // [mf(channel)][nf(cos/sin)]
    #pragma unroll
    for (int mf = 0; mf < 2; ++mf)
        #pragma unroll
        for (int nf = 0; nf < 2; ++nf)
            #pragma unroll
            for (int r = 0; r < 16; ++r) acc[mf][nf][r] = 0.0f;

    int cur = 0;
    for (int s = 0; s < 32; ++s) {
        const int kkn = (s + 1) & 31;                    // wrap at tail (drained later)
        const int nxt = cur ^ 1;
        // a. A-loads for kk+1 (clamped; uniform issue count)
        const int i0 = ibase + kkn * 16;
        const bool o0 = (i0 >= 0) && (i0 < L_IN);
        const bool o1 = (i0 + 1 >= 0) && (i0 + 1 < L_IN);
        const int c0 = i0 < 0 ? 0 : (i0 >= L_IN ? L_IN - 1 : i0);
        const int c1 = (i0 + 1) < 0 ? 0 : ((i0 + 1) >= L_IN ? L_IN - 1 : (i0 + 1));
        const float v0 = xst[c0];
        const float v1 = xst[c1];
        // b. W DMAs for kk+1
        {
            char* wb = smem + WRING_OFF + (nxt * 8 + g) * 4096;
            const short* wh = wgH + kkn * 512;
            const short* wl = wgL + kkn * 512;
            gload_lds16(wh,          wb);
            gload_lds16(wh + 16384,  wb + 1024);
            gload_lds16(wl,          wb + 2048);
            gload_lds16(wl + 16384,  wb + 3072);
        }
        // c. counted wait: drains W[cur] (4 oldest); leaves {2 A-loads, 4 DMAs}
        asm volatile("s_waitcnt vmcnt(6)" ::: "memory");
        // d. fragment reads (all linear/uniform-permuted: conflict-free)
        const char* wr = smem + WRING_OFF + (cur * 8 + g) * 4096 + lane * 16;
        bf16x8 bh0 = *(const bf16x8*)(wr);
        bf16x8 bh1 = *(const bf16x8*)(wr + 1024);
        bf16x8 bl0 = *(const bf16x8*)(wr + 2048);
        bf16x8 bl1 = *(const bf16x8*)(wr + 3072);
        const char* ar = smem + ARING_OFF + cur * 4096;
        bf16x8 ah0 = *(const bf16x8*)(ar + ard0);
        bf16x8 ah1 = *(const bf16x8*)(ar + ard1);
        bf16x8 al0 = *(const bf16x8*)(ar + 2048 + ard0);
        bf16x8 al1 = *(const bf16x8*)(ar + 2048 + ard1);
        // 12 MFMA: hh, hl, lh (same-acc dependents 4 apart)
        acc[0][0] = __builtin_amdgcn_mfma_f32_32x32x16_bf16(ah0, bh0, acc[0][0], 0, 0, 0);
        acc[0][1] = __builtin_amdgcn_mfma_f32_32x32x16_bf16(ah0, bh1, acc[0][1], 0, 0, 0);
        acc[1][0] = __builtin_amdgcn_mfma_f32_32x32x16_bf16(ah1, bh0, acc[1][0], 0, 0, 0);
        acc[1][1] = __builtin_amdgcn_mfma_f32_32x32x16_bf16(ah1, bh1, acc[1][1], 0, 0, 0);
        acc[0][0] = __builtin_amdgcn_mfma_f32_32x32x16_bf16(ah0, bl0, acc[0][0], 0, 0, 0);
        acc[0][1] = __builtin_amdgcn_mfma_f32_32x32x16_bf16(ah0, bl1, acc[0][1], 0, 0, 0);
        acc[1][0] = __builtin_amdgcn_mfma_f32_32x32x16_bf16(ah1, bl0, acc[1][0], 0, 0, 0);
        acc[1][1] = __builtin_amdgcn_mfma_f32_32x32x16_bf16(ah1, bl1, acc[1][1], 0, 0, 0);
        acc[0][0] = __builtin_amdgcn_mfma_f32_32x32x16_bf16(al0, bh0, acc[0][0], 0, 0, 0);
        acc[0][1] = __builtin_amdgcn_mfma_f32_32x32x16_bf16(al0, bh1, acc[0][1], 0, 0, 0);
        acc[1][0] = __builtin_amdgcn_mfma_f32_32x32x16_bf16(al1, bh0, acc[1][0], 0, 0, 0);
        acc[1][1] = __builtin_amdgcn_mfma_f32_32x32x16_bf16(al1, bh1, acc[1][1], 0, 0, 0);
        // e/f. convert + publish A[kk+1]  (A-load wait here = vmcnt(4): DMAs stay in flight)
        {
            float w0 = o0 ? v0 : 0.0f;
            float w1 = o1 ? v1 : 0.0f;
            short h0 = f2bf(w0), h1 = f2bf(w1);
            short l0 = f2bf(w0 - bf2f(h0)), l1 = f2bf(w1 - bf2f(h1));
            *(unsigned*)(smem + ARING_OFF + nxt * 4096 + a_waddr) =
                (unsigned)(unsigned short)h0 | ((unsigned)(unsigned short)h1 << 16);
            *(unsigned*)(smem + ARING_OFF + nxt * 4096 + 2048 + a_waddr) =
                (unsigned)(unsigned short)l0 | ((unsigned)(unsigned short)l1 << 16);
        }
        asm volatile("s_waitcnt lgkmcnt(0)" ::: "memory");
        __builtin_amdgcn_s_barrier();
        cur = nxt;
    }

    // ---- epilogue: p = re^2+im^2 -> LDS transpose S[64][257] -> coalesced stores ----
    // C/D layout (32x32): n = lane&31, m = (r&3) + 8*(r>>2) + 4*(lane>>5)
    __syncthreads();                       // full drain (incl. wrapped tail DMAs); then reuse LDS as S
    const bool nyq = (g == 0) && (col == 0);
    float pmax = 0.0f;
    #pragma unroll
    for (int mf = 0; mf < 2; ++mf) {       // mf = channel
        #pragma unroll
        for (int r = 0; r < 16; ++r) {
            const int m   = (r & 3) + 8 * (r >> 2) + 4 * half;
            const int row = m * 2 + mf;
            const float re = acc[mf][0][r];
            const float im = acc[mf][1][r];
            const float imq = nyq ? 0.0f : im;
            float p = fmaxf(re * re + imq * imq, AMIN);
            pmax = fmaxf(pmax, p);
            S[row * 257 + g * 32 + col] = p;   // bank (row+col)%32: conflict-free
            if (nyq) {                     // sin-frag col0 carries f=256 re
                float pn = fmaxf(im * im, AMIN);
                pmax = fmaxf(pmax, pn);
                S[row * 257 + 256] = pn;
            }
        }
    }
    #pragma unroll
    for (int off = 32; off > 0; off >>= 1)
        pmax = fmaxf(pmax, __shfl_down(pmax, off, 64));
    if (lane == 0) wmax[g] = pmax;
    __syncthreads();                       // guards both wmax and S
    if (tid == 0) {
        float m2 = wmax[0];
        #pragma unroll
        for (int w = 1; w < 8; ++w) m2 = fmaxf(m2, wmax[w]);
        atomicMax(wsmax, __float_as_uint(m2));
    }
    // per f: 64 consecutive floats (t local 0..31 x mf) = 16 float4; 4112 float4 total
    float* obase = out + (size_t)b * 526336 + (size_t)tt * 64;
    for (int qq = tid; qq < 257 * 16; qq += 512) {
        const int f = qq >> 4, part = qq & 15;
        float4 vv;
        vv.x = S[(part * 4 + 0) * 257 + f];
        vv.y = S[(part * 4 + 1) * 257 + f];
        vv.z = S[(part * 4 + 2) * 257 + f];
        vv.w = S[(part * 4 + 3) * 257 + f];
        *(float4*)(obase + (size_t)f * 2048 + part * 4) = vv;
    }
}

__global__ __launch_bounds__(256) void finalize_kernel(
    float* __restrict__ out, const unsigned* __restrict__ ws_max, int n4)
{
    const int i = blockIdx.x * 256 + threadIdx.x;
    if (i >= n4) return;
    const float mlog = 10.0f * log10f(__uint_as_float(*ws_max));
    float4 p = ((const float4*)out)[i];
    float4 v;
    v.x = fmaxf(10.0f * log10f(p.x) - mlog, -DRANGE);
    v.y = fmaxf(10.0f * log10f(p.y) - mlog, -DRANGE);
    v.z = fmaxf(10.0f * log10f(p.z) - mlog, -DRANGE);
    v.w = fmaxf(10.0f * log10f(p.w) - mlog, -DRANGE);
    ((float4*)out)[i] = v;
}

extern "C" void kernel_launch(void* const* d_in, const int* in_sizes, int n_in,
                              void* d_out, int out_size, void* d_ws, size_t ws_size,
                              hipStream_t stream) {
    const float* x  = (const float*)d_in[0];
    const float* kr = (const float*)d_in[1];
    const float* ki = (const float*)d_in[2];
    float* out      = (float*)d_out;

    unsigned* wsmax = (unsigned*)d_ws;
    short* whi      = (short*)((char*)d_ws + WS_HI_OFF);
    short* wlo      = (short*)((char*)d_ws + WS_HI_OFF + WS_HALF);

    wconv_kernel<<<128, 256, 0, stream>>>(kr, ki, whi, wlo, wsmax);

    const int nblocks = 32 * 32;       // b * t-tiles (32 frames per tile)
    spec_kernel<<<nblocks, 512, 0, stream>>>(x, whi, wlo, out, wsmax);

    const int n4 = N4_OUT;
    finalize_kernel<<<(n4 + 255) / 256, 256, 0, stream>>>(out, wsmax, n4);
}

// Round 10
// 211.626 us; speedup vs baseline: 1.1452x; 1.0863x over previous
//
#include <hip/hip_runtime.h>
#include <math.h>

#define L_IN     262144
#define N_FRAME  1024
#define AMIN     1e-10f
#define DRANGE   80.0f
#define UNITS_CH 1056            // (32 frames * 256 hop + 256)/8 16B-units per channel
#define WS_HI_OFF   4096
#define WS_HALF     524288       // 16 frags * 32 kk * 64 lanes * 16B
#define N4_OUT   ((32 * 257 * 1024 * 2) / 4)   // float4 count of the real output

typedef short bf16x8 __attribute__((ext_vector_type(8)));
typedef short bf16x4 __attribute__((ext_vector_type(4)));
typedef float f32x16 __attribute__((ext_vector_type(16)));

__device__ __forceinline__ short f2bf(float f) {           // fp32 -> bf16 RNE
    unsigned u = __float_as_uint(f);
    u = (u + 0x7FFFu + ((u >> 16) & 1u)) >> 16;
    return (short)u;
}
__device__ __forceinline__ float bf2f(short h) {
    return __uint_as_float(((unsigned)(unsigned short)h) << 16);
}
__device__ __forceinline__ int swz(int u) { return u ^ ((u >> 5) & 7); }

// W -> bf16 hi/lo in 32x32x16 MFMA B-frag order.  (unchanged)
__global__ __launch_bounds__(256) void wconv_kernel(
    const float* __restrict__ kr, const float* __restrict__ ki,
    short* __restrict__ whi, short* __restrict__ wlo, unsigned* __restrict__ wsmax)
{
    if (blockIdx.x == 0 && threadIdx.x == 0) wsmax[0] = 0u;
    const int tid  = threadIdx.x;
    const int pair = blockIdx.x * 4 + (tid >> 6);   // (fi,kk) in [0,512)
    const int lane = tid & 63;
    const int fi = pair >> 5, kk = pair & 31;
    const int g = fi >> 1, nf = fi & 1;
    const int n  = lane & 31;
    const int k0 = kk * 16 + (lane >> 5) * 8;
    const int f  = g * 32 + n;
    bf16x8 h8, l8;
    #pragma unroll
    for (int j = 0; j < 8; ++j) {
        const int k = k0 + j;
        float w;
        if (nf == 1 && g == 0 && n == 0) w = kr[k * 257 + 256];   // Nyquist column
        else                             w = (nf ? ki : kr)[k * 257 + f];
        short hh = f2bf(w);
        h8[j] = hh;
        l8[j] = f2bf(w - bf2f(hh));
    }
    const int off = ((fi * 32 + kk) * 64 + lane) * 8;
    *(bf16x8*)(whi + off) = h8;
    *(bf16x8*)(wlo + off) = l8;
}

// One block: 32 frames x 2 channels (M=64) x all 257 filters; 8 waves, wave = filter group.
// r6 structure (best: 112us) + WAVE SKEW: wave g iterates kk starting at 4g (wrapping).
// Mechanism: after the stage barrier all 8 waves run identical code in lockstep -> all
// 4 waves/SIMD load together (MFMA idle) then MFMA together (mem idle) — a convoy
// (m233's 2-phase stall, arising spontaneously).  The skew pins the 4 waves/SIMD at 4
// different K-phases so load windows overlap MFMA clusters.  fp32 acc order changes
// per wave: rounding-level only.  Regs <=128 total (60 VGPR + 64 AGPR) -> 16 waves/CU,
// 2 blocks/CU (LDS 2x68KB).  (512,4) safe here: genuine need ~110 regs (round-6 proven).
__global__ __launch_bounds__(512, 4) void spec_kernel(
    const float* __restrict__ x,
    const short* __restrict__ whi, const short* __restrict__ wlo,
    float* __restrict__ out, unsigned* __restrict__ wsmax)
{
    // A hi/lo buffers; reused after the K-loop as the fp32 output-transpose buffer S.
    __shared__ __align__(16) char smem[2 * 2 * UNITS_CH * 8 * sizeof(short)]; // 67584 B
    __shared__ float wmax[8];
    short* Ah = (short*)smem;                                   // 33792 B
    short* Al = (short*)(smem + 2 * UNITS_CH * 8 * sizeof(short));
    float* S  = (float*)smem;                                   // [64][257] = 65792 B

    const int blk = blockIdx.x;
    const int tt  = blk & 31;
    const int b   = blk >> 5;
    const int tid = threadIdx.x;
    const int lane = tid & 63;
    const int g    = tid >> 6;          // wave = filter group
    const int col  = lane & 31;
    const int half = lane >> 5;

    // ---- stage A: rolled; wave-contiguous 256-sample chunks, lane i float4 @ +16B*i ----
    const int s_origin = tt * 8192 - 128;
    for (int cc = g; cc < 66; cc += 8) {
        const int ch   = (cc >= 33) ? 1 : 0;
        const int c    = cc - ch * 33;
        const int base = s_origin + c * 256;
        const float* xp = x + ((size_t)b * 2 + ch) * L_IN;
        const int i4 = base + lane * 4;
        float v[4];
        if (base >= 0 && base + 256 <= L_IN) {
            float4 p = *(const float4*)(xp + i4);
            v[0] = p.x; v[1] = p.y; v[2] = p.z; v[3] = p.w;
        } else {
            #pragma unroll
            for (int j = 0; j < 4; ++j) {
                const int idx = i4 + j;
                v[j] = (idx >= 0 && idx < L_IN) ? xp[idx] : 0.0f;
            }
        }
        bf16x4 h4, l4;
        #pragma unroll
        for (int j = 0; j < 4; ++j) {
            short hh = f2bf(v[j]);
            h4[j] = hh;
            l4[j] = f2bf(v[j] - bf2f(hh));
        }
        const int u = c * 32 + (lane >> 1);
        const int e = (ch * UNITS_CH + swz(u)) * 8 + (lane & 1) * 4;
        *(bf16x4*)&Ah[e] = h4;     // ds_write_b64
        *(bf16x4*)&Al[e] = l4;
    }
    __syncthreads();

    // ---- K loop: barrier-free, kh-serial, JIT loads; wave-skewed kk order ----
    f32x16 acc[2][2];                  // [mf(channel)][nf(cos/sin)]
    #pragma unroll
    for (int mf = 0; mf < 2; ++mf)
        #pragma unroll
        for (int nf = 0; nf < 2; ++nf)
            #pragma unroll
            for (int r = 0; r < 16; ++r) acc[mf][nf][r] = 0.0f;

    const int laneoff = lane * 8;
    const short* whiW = whi + (g * 2) * 32 * 64 * 8 + laneoff;   // nf stride = 32*64*8
    const short* wloW = wlo + (g * 2) * 32 * 64 * 8 + laneoff;

    for (int s = 0; s < 32; ++s) {
        const int kk = (s + g * 4) & 31;           // wave skew: 4 waves/SIMD at 4 phases
        const int u0 = col * 32 + kk * 2 + half;
        const int e0 = swz(u0) * 8;
        const int e1 = (UNITS_CH + swz(u0)) * 8;
        const int wo = kk * 64 * 8;
        // hh
        bf16x8 bh0 = *(const bf16x8*)(whiW + wo);
        bf16x8 bh1 = *(const bf16x8*)(whiW + 32 * 64 * 8 + wo);
        bf16x8 ah0 = *(const bf16x8*)&Ah[e0];
        bf16x8 ah1 = *(const bf16x8*)&Ah[e1];
        acc[0][0] = __builtin_amdgcn_mfma_f32_32x32x16_bf16(ah0, bh0, acc[0][0], 0, 0, 0);
        acc[0][1] = __builtin_amdgcn_mfma_f32_32x32x16_bf16(ah0, bh1, acc[0][1], 0, 0, 0);
        acc[1][0] = __builtin_amdgcn_mfma_f32_32x32x16_bf16(ah1, bh0, acc[1][0], 0, 0, 0);
        acc[1][1] = __builtin_amdgcn_mfma_f32_32x32x16_bf16(ah1, bh1, acc[1][1], 0, 0, 0);
        // hl
        bf16x8 bl0 = *(const bf16x8*)(wloW + wo);
        bf16x8 bl1 = *(const bf16x8*)(wloW + 32 * 64 * 8 + wo);
        acc[0][0] = __builtin_amdgcn_mfma_f32_32x32x16_bf16(ah0, bl0, acc[0][0], 0, 0, 0);
        acc[0][1] = __builtin_amdgcn_mfma_f32_32x32x16_bf16(ah0, bl1, acc[0][1], 0, 0, 0);
        acc[1][0] = __builtin_amdgcn_mfma_f32_32x32x16_bf16(ah1, bl0, acc[1][0], 0, 0, 0);
        acc[1][1] = __builtin_amdgcn_mfma_f32_32x32x16_bf16(ah1, bl1, acc[1][1], 0, 0, 0);
        // lh
        bf16x8 al0 = *(const bf16x8*)&Al[e0];
        bf16x8 al1 = *(const bf16x8*)&Al[e1];
        acc[0][0] = __builtin_amdgcn_mfma_f32_32x32x16_bf16(al0, bh0, acc[0][0], 0, 0, 0);
        acc[0][1] = __builtin_amdgcn_mfma_f32_32x32x16_bf16(al0, bh1, acc[0][1], 0, 0, 0);
        acc[1][0] = __builtin_amdgcn_mfma_f32_32x32x16_bf16(al1, bh0, acc[1][0], 0, 0, 0);
        acc[1][1] = __builtin_amdgcn_mfma_f32_32x32x16_bf16(al1, bh1, acc[1][1], 0, 0, 0);
    }

    // ---- epilogue: p = re^2+im^2 -> LDS transpose S[64][257] -> coalesced stores ----
    // C/D layout (32x32): n = lane&31, m = (r&3) + 8*(r>>2) + 4*(lane>>5)
    __syncthreads();                       // all A-reads done; reuse LDS as S
    const bool nyq = (g == 0) && (col == 0);
    float pmax = 0.0f;
    #pragma unroll
    for (int mf = 0; mf < 2; ++mf) {       // mf = channel
        #pragma unroll
        for (int r = 0; r < 16; ++r) {
            const int m   = (r & 3) + 8 * (r >> 2) + 4 * half;
            const int row = m * 2 + mf;
            const float re = acc[mf][0][r];
            const float im = acc[mf][1][r];
            const float imq = nyq ? 0.0f : im;
            float p = fmaxf(re * re + imq * imq, AMIN);
            pmax = fmaxf(pmax, p);
            S[row * 257 + g * 32 + col] = p;   // bank (row+col)%32: conflict-free
            if (nyq) {                     // sin-frag col0 carries f=256 re
                float pn = fmaxf(im * im, AMIN);
                pmax = fmaxf(pmax, pn);
                S[row * 257 + 256] = pn;
            }
        }
    }
    #pragma unroll
    for (int off = 32; off > 0; off >>= 1)
        pmax = fmaxf(pmax, __shfl_down(pmax, off, 64));
    if (lane == 0) wmax[g] = pmax;
    __syncthreads();                       // guards both wmax and S
    if (tid == 0) {
        float m2 = wmax[0];
        #pragma unroll
        for (int w = 1; w < 8; ++w) m2 = fmaxf(m2, wmax[w]);
        atomicMax(wsmax, __float_as_uint(m2));
    }
    // per f: 64 consecutive floats (t local 0..31 x mf) = 16 float4; 4112 float4 total
    float* obase = out + (size_t)b * 526336 + (size_t)tt * 64;
    for (int q = tid; q < 257 * 16; q += 512) {
        const int f = q >> 4, part = q & 15;
        float4 vv;
        vv.x = S[(part * 4 + 0) * 257 + f];
        vv.y = S[(part * 4 + 1) * 257 + f];
        vv.z = S[(part * 4 + 2) * 257 + f];
        vv.w = S[(part * 4 + 3) * 257 + f];
        *(float4*)(obase + (size_t)f * 2048 + part * 4) = vv;
    }
}

__global__ __launch_bounds__(256) void finalize_kernel(
    float* __restrict__ out, const unsigned* __restrict__ ws_max, int n4)
{
    const int i = blockIdx.x * 256 + threadIdx.x;
    if (i >= n4) return;
    const float mlog = 10.0f * log10f(__uint_as_float(*ws_max));
    float4 p = ((const float4*)out)[i];
    float4 v;
    v.x = fmaxf(10.0f * log10f(p.x) - mlog, -DRANGE);
    v.y = fmaxf(10.0f * log10f(p.y) - mlog, -DRANGE);
    v.z = fmaxf(10.0f * log10f(p.z) - mlog, -DRANGE);
    v.w = fmaxf(10.0f * log10f(p.w) - mlog, -DRANGE);
    ((float4*)out)[i] = v;
}

extern "C" void kernel_launch(void* const* d_in, const int* in_sizes, int n_in,
                              void* d_out, int out_size, void* d_ws, size_t ws_size,
                              hipStream_t stream) {
    const float* x  = (const float*)d_in[0];
    const float* kr = (const float*)d_in[1];
    const float* ki = (const float*)d_in[2];
    float* out      = (float*)d_out;

    unsigned* wsmax = (unsigned*)d_ws;
    short* whi      = (short*)((char*)d_ws + WS_HI_OFF);
    short* wlo      = (short*)((char*)d_ws + WS_HI_OFF + WS_HALF);

    wconv_kernel<<<128, 256, 0, stream>>>(kr, ki, whi, wlo, wsmax);

    const int nblocks = 32 * 32;       // b * t-tiles (32 frames per tile)
    spec_kernel<<<nblocks, 512, 0, stream>>>(x, whi, wlo, out, wsmax);

    const int n4 = N4_OUT;
    finalize_kernel<<<(n4 + 255) / 256, 256, 0, stream>>>(out, wsmax, n4);
}